// Round 1
// baseline (766.813 us; speedup 1.0000x reference)
//
#include <hip/hip_runtime.h>
#include <hip/hip_bf16.h>
#include <cstdint>

#define AS_GLOBAL __attribute__((address_space(1)))
#define AS_LDS    __attribute__((address_space(3)))

typedef __attribute__((ext_vector_type(8))) short bf16x8;
typedef __attribute__((ext_vector_type(4))) float f32x4;

static __device__ __forceinline__ ushort f2bf(float x) {
    union { float f; uint32_t u; } c;
    c.f = x;
    uint32_t u = c.u;
    u += 0x7fffu + ((u >> 16) & 1u);   // round-to-nearest-even
    return (ushort)(u >> 16);
}

// ---- async global->LDS, 16B per lane. LDS dest must be uniform base + lane*16.
static __device__ __forceinline__ void gload_lds16(const void* g, void* l) {
    __builtin_amdgcn_global_load_lds(
        (const AS_GLOBAL uint32_t*)(uintptr_t)g,
        (AS_LDS uint32_t*)(uint32_t)(uintptr_t)l,
        16, 0, 0);
}

// ---------------- fp32 -> bf16 convert (vectorized) ----------------
__global__ __launch_bounds__(256)
void cvt_f32_bf16(const float4* __restrict__ in, ushort4* __restrict__ out, int n4) {
    int i = blockIdx.x * 256 + threadIdx.x;
    int stride = gridDim.x * 256;
    for (; i < n4; i += stride) {
        float4 v = in[i];
        ushort4 o;
        o.x = f2bf(v.x); o.y = f2bf(v.y); o.z = f2bf(v.z); o.w = f2bf(v.w);
        out[i] = o;
    }
}

// ---------------- [K,N] fp32 -> [N,K] bf16 transpose ----------------
__global__ __launch_bounds__(256)
void transpose_to_bf16(const float* __restrict__ w, ushort* __restrict__ wt, int K, int N) {
    __shared__ float tile[32][33];
    int bn = blockIdx.x * 32;   // n tile
    int bk = blockIdx.y * 32;   // k tile
    int tx = threadIdx.x & 31, ty = threadIdx.x >> 5;   // 32 x 8
    #pragma unroll
    for (int i = 0; i < 32; i += 8)
        tile[ty + i][tx] = w[(size_t)(bk + ty + i) * N + bn + tx];
    __syncthreads();
    #pragma unroll
    for (int i = 0; i < 32; i += 8)
        wt[(size_t)(bn + ty + i) * K + bk + tx] = f2bf(tile[tx][ty + i]);
}

// ---------------- GEMM: C[M,N] = A[M,K](bf16) * Bt[N,K](bf16), fused epilogue ----------------
// EPI: 0 = none, 1 = sigmoid, 2 = exp.  OUT_BF: write ushort(bf16) instead of float.
template<int EPI, int OUT_BF>
__global__ __launch_bounds__(256)
void gemm_bt_epi(const ushort* __restrict__ A, const ushort* __restrict__ Bt,
                 void* __restrict__ Cv, int M, int N, int K) {
    __shared__ ushort sA[128 * 32];   // [row][k] row-major, 8KB
    __shared__ ushort sB[128 * 32];
    const int tid  = threadIdx.x;
    const int wid  = tid >> 6;
    const int lane = tid & 63;
    const int wr = wid >> 1, wc = wid & 1;      // 2x2 waves of 64x64
    const int bn = blockIdx.x, bm = blockIdx.y; // x fast over N panels -> A-tile reuse in L2
    const int m0 = bm * 128, n0 = bn * 128;
    const int lr = lane & 15;
    const int kb = lane >> 4;

    f32x4 acc[4][4] = {};

    for (int k0 = 0; k0 < K; k0 += 32) {
        #pragma unroll
        for (int i = 0; i < 2; i++) {
            int c = i * 256 + wid * 64 + lane;   // 16B chunk id, 512 total
            int row = c >> 2, kh = c & 3;
            const ushort* gA = A  + (size_t)(m0 + row) * K + k0 + kh * 8;
            const ushort* gB = Bt + (size_t)(n0 + row) * K + k0 + kh * 8;
            gload_lds16(gA, &sA[(size_t)c * 8]);
            gload_lds16(gB, &sB[(size_t)c * 8]);
        }
        __syncthreads();
        bf16x8 af[4], bfr[4];
        #pragma unroll
        for (int m = 0; m < 4; m++)
            af[m] = *(const bf16x8*)&sA[(wr * 64 + m * 16 + lr) * 32 + kb * 8];
        #pragma unroll
        for (int n = 0; n < 4; n++)
            bfr[n] = *(const bf16x8*)&sB[(wc * 64 + n * 16 + lr) * 32 + kb * 8];
        #pragma unroll
        for (int m = 0; m < 4; m++)
            #pragma unroll
            for (int n = 0; n < 4; n++)
                acc[m][n] = __builtin_amdgcn_mfma_f32_16x16x32_bf16(af[m], bfr[n], acc[m][n], 0, 0, 0);
        __syncthreads();
    }

    float*  Cf = (float*)Cv;
    ushort* Cb = (ushort*)Cv;
    #pragma unroll
    for (int m = 0; m < 4; m++) {
        #pragma unroll
        for (int n = 0; n < 4; n++) {
            #pragma unroll
            for (int r = 0; r < 4; r++) {
                int row = m0 + wr * 64 + m * 16 + (lane >> 4) * 4 + r;
                int col = n0 + wc * 64 + n * 16 + (lane & 15);
                float v = acc[m][n][r];
                if (EPI == 1) v = 1.0f / (1.0f + __expf(-v));
                else if (EPI == 2) v = __expf(v);
                size_t idx = (size_t)row * N + col;
                if (OUT_BF) Cb[idx] = f2bf(v);
                else        Cf[idx] = v;
            }
        }
    }
}

// ---------------- scan pass A: per-chunk sums ----------------
// partials layout: [chunk][b*H + h]  (chunk-major so pass B/C are coalesced)
__global__ __launch_bounds__(256)
void scan_partials(const float* __restrict__ ke, const float* __restrict__ ev,
                   float* __restrict__ pke, float* __restrict__ pkv,
                   int S, int H, int chunk, int BH) {
    int h = blockIdx.x * 256 + threadIdx.x;
    int c = blockIdx.y;
    int b = blockIdx.z;
    size_t base = ((size_t)b * S + (size_t)c * chunk) * H + h;
    float ske = 0.f, skv = 0.f;
    for (int s = 0; s < chunk; s++) {
        float e  = ke[base + (size_t)s * H];
        float vv = ev[base + (size_t)s * H];
        ske += e;
        skv += e * vv;
    }
    size_t pidx = (size_t)c * BH + b * H + h;
    pke[pidx] = ske;
    pkv[pidx] = skv;
}

// ---------------- scan pass B: exclusive prefix over chunks ----------------
__global__ __launch_bounds__(256)
void scan_offsets(float* __restrict__ pke, float* __restrict__ pkv, int nch, int BH) {
    int i = blockIdx.x * blockDim.x + threadIdx.x;
    if (i >= BH) return;
    float rke = 0.f, rkv = 0.f;
    for (int c = 0; c < nch; c++) {
        size_t idx = (size_t)c * BH + i;
        float a = pke[idx], b = pkv[idx];
        pke[idx] = rke; pkv[idx] = rkv;
        rke += a; rkv += b;
    }
}

// ---------------- scan pass C: inclusive scan + y = sigmoid(emb_q)*(kv/ke), bf16 out ----------------
__global__ __launch_bounds__(256)
void scan_final(const float* __restrict__ ke, const float* __restrict__ ev,
                const float* __restrict__ sq,
                const float* __restrict__ pke, const float* __restrict__ pkv,
                ushort* __restrict__ ybf, int S, int H, int chunk, int BH) {
    int h = blockIdx.x * 256 + threadIdx.x;
    int c = blockIdx.y;
    int b = blockIdx.z;
    size_t pidx = (size_t)c * BH + b * H + h;
    float rke = pke[pidx], rkv = pkv[pidx];
    size_t base = ((size_t)b * S + (size_t)c * chunk) * H + h;
    for (int s = 0; s < chunk; s++) {
        size_t idx = base + (size_t)s * H;
        float e = ke[idx];
        rke += e;
        rkv += e * ev[idx];
        float y = sq[idx] * (rkv / rke);
        ybf[idx] = f2bf(y);
    }
}

extern "C" void kernel_launch(void* const* d_in, const int* in_sizes, int n_in,
                              void* d_out, int out_size, void* d_ws, size_t ws_size,
                              hipStream_t stream) {
    const float* q   = (const float*)d_in[0];
    const float* k   = (const float*)d_in[1];
    const float* v   = (const float*)d_in[2];
    const float* w_q = (const float*)d_in[3];
    const float* w_k = (const float*)d_in[4];
    const float* w_v = (const float*)d_in[5];
    const float* w_p = (const float*)d_in[6];
    float* out = (float*)d_out;

    const int B = 4, S = 8192, H = 1024;
    const int M = B * S;                 // 32768
    const size_t MH = (size_t)M * H;     // 33,554,432
    const int NCH = 128, CHUNK = S / NCH; // 64
    const int BH = B * H;                // 4096

    char* ws = (char*)d_ws;
    size_t off = 0;
    auto alloc = [&](size_t bytes) -> char* {
        char* p = ws + off;
        off += (bytes + 255) & ~(size_t)255;
        return p;
    };
    ushort* abuf = (ushort*)alloc(MH * 2);          // shared bf16 input buffer (q/k/v/y)
    ushort* wqt  = (ushort*)alloc((size_t)H * H * 2);
    ushort* wkt  = (ushort*)alloc((size_t)H * H * 2);
    ushort* wvt  = (ushort*)alloc((size_t)H * H * 2);
    ushort* wpt  = (ushort*)alloc((size_t)H * H * 2);
    float*  sq   = (float*)alloc(MH * 4);
    float*  ke   = (float*)alloc(MH * 4);
    float*  ev   = (float*)alloc(MH * 4);
    float*  pke  = (float*)alloc((size_t)NCH * BH * 4);
    float*  pkv  = (float*)alloc((size_t)NCH * BH * 4);
    // total ~ 480 MB

    const int n4 = (int)(MH / 4);
    dim3 tg(H / 32, H / 32);
    dim3 gg(H / 128, M / 128);   // x over N panels (A-tile L2 reuse), y over M
    dim3 gs(H / 256, NCH, B);

    // weights
    transpose_to_bf16<<<tg, 256, 0, stream>>>(w_q, wqt, H, H);
    transpose_to_bf16<<<tg, 256, 0, stream>>>(w_k, wkt, H, H);
    transpose_to_bf16<<<tg, 256, 0, stream>>>(w_v, wvt, H, H);
    transpose_to_bf16<<<tg, 256, 0, stream>>>(w_p, wpt, H, H);

    // sq = sigmoid(q @ w_q)
    cvt_f32_bf16<<<2048, 256, 0, stream>>>((const float4*)q, (ushort4*)abuf, n4);
    gemm_bt_epi<1, 0><<<gg, 256, 0, stream>>>(abuf, wqt, sq, M, H, H);
    // ke = exp(k @ w_k)
    cvt_f32_bf16<<<2048, 256, 0, stream>>>((const float4*)k, (ushort4*)abuf, n4);
    gemm_bt_epi<2, 0><<<gg, 256, 0, stream>>>(abuf, wkt, ke, M, H, H);
    // ev = v @ w_v
    cvt_f32_bf16<<<2048, 256, 0, stream>>>((const float4*)v, (ushort4*)abuf, n4);
    gemm_bt_epi<0, 0><<<gg, 256, 0, stream>>>(abuf, wvt, ev, M, H, H);

    // hierarchical scan over S
    scan_partials<<<gs, 256, 0, stream>>>(ke, ev, pke, pkv, S, H, CHUNK, BH);
    scan_offsets<<<16, 256, 0, stream>>>(pke, pkv, NCH, BH);
    scan_final<<<gs, 256, 0, stream>>>(ke, ev, sq, pke, pkv, abuf, S, H, CHUNK, BH);

    // out = y @ w_p
    gemm_bt_epi<0, 0><<<gg, 256, 0, stream>>>(abuf, wpt, out, M, H, H);
}

// Round 2
// 684.270 us; speedup vs baseline: 1.1206x; 1.1206x over previous
//
#include <hip/hip_runtime.h>
#include <hip/hip_bf16.h>
#include <cstdint>

#define AS_GLOBAL __attribute__((address_space(1)))
#define AS_LDS    __attribute__((address_space(3)))

typedef __attribute__((ext_vector_type(8))) short bf16x8;
typedef __attribute__((ext_vector_type(4))) float f32x4;

static __device__ __forceinline__ ushort f2bf(float x) {
    union { float f; uint32_t u; } c;
    c.f = x;
    uint32_t u = c.u;
    u += 0x7fffu + ((u >> 16) & 1u);   // RTNE
    return (ushort)(u >> 16);
}
static __device__ __forceinline__ float bf2f(ushort u) {
    union { uint32_t i; float f; } c;
    c.i = ((uint32_t)u) << 16;
    return c.f;
}

// ---- async global->LDS, 16B per lane. LDS dest must be uniform base + lane*16.
static __device__ __forceinline__ void gload_lds16(const void* g, void* l) {
    __builtin_amdgcn_global_load_lds(
        (const AS_GLOBAL uint32_t*)(uintptr_t)g,
        (AS_LDS uint32_t*)(uint32_t)(uintptr_t)l,
        16, 0, 0);
}

// ---------------- [K,N] fp32 -> [N,K] bf16 transpose ----------------
__global__ __launch_bounds__(256)
void transpose_to_bf16(const float* __restrict__ w, ushort* __restrict__ wt, int K, int N) {
    __shared__ float tile[32][33];
    int bn = blockIdx.x * 32;
    int bk = blockIdx.y * 32;
    int tx = threadIdx.x & 31, ty = threadIdx.x >> 5;
    #pragma unroll
    for (int i = 0; i < 32; i += 8)
        tile[ty + i][tx] = w[(size_t)(bk + ty + i) * N + bn + tx];
    __syncthreads();
    #pragma unroll
    for (int i = 0; i < 32; i += 8)
        wt[(size_t)(bn + ty + i) * K + bk + tx] = f2bf(tile[tx][ty + i]);
}

// ---------------- GEMM: C[M,N] = A[M,K] * Bt[N,K](bf16), double-buffered ----------------
// EPI: 0=none 1=sigmoid 2=exp.  A_F32: A is fp32 (fused cvt).  OUT_BF: bf16 C.
template<int EPI, int A_F32, int OUT_BF>
__global__ __launch_bounds__(256)
void gemm_bt(const void* __restrict__ Av, const ushort* __restrict__ Bt,
             void* __restrict__ Cv, int M, int N, int K) {
    __shared__ ushort sA[2][128 * 32];
    __shared__ ushort sB[2][128 * 32];
    const int tid  = threadIdx.x;
    const int wid  = tid >> 6;
    const int lane = tid & 63;
    const int wr = wid >> 1, wc = wid & 1;

    // XCD-aware bijective swizzle: each XCD gets a contiguous bm chunk, bn fastest.
    // nwg = (M/128)*(N/128), N/128 == 8 here, nwg % 8 == 0.
    const int mPanels = M / 128;
    const int wg = blockIdx.x;
    const int xcd = wg & 7, local = wg >> 3;
    const int bm = xcd * (mPanels / 8) + (local >> 3);
    const int bn = local & 7;
    const int m0 = bm * 128, n0 = bn * 128;
    const int lr = lane & 15;
    const int kb = lane >> 4;

    const float*  Af = (const float*)Av;
    const ushort* Ab = (const ushort*)Av;

    f32x4 acc[4][4] = {};
    float4 fa0, fa1, fa2, fa3;                 // in-flight fp32 A (reg stage)
    const int ar = tid >> 1;                   // A row 0..127
    const int ah = (tid & 1) * 16;             // A k-offset 0 or 16

    auto stageB = [&](int k0, int bufi) {
        #pragma unroll
        for (int i = 0; i < 2; i++) {
            int c = i * 256 + tid;
            int row = c >> 2, kh = c & 3;
            gload_lds16(Bt + (size_t)(n0 + row) * K + k0 + kh * 8, &sB[bufi][c * 8]);
        }
    };
    auto stageA_bf = [&](int k0, int bufi) {
        #pragma unroll
        for (int i = 0; i < 2; i++) {
            int c = i * 256 + tid;
            int row = c >> 2, kh = c & 3;
            gload_lds16(Ab + (size_t)(m0 + row) * K + k0 + kh * 8, &sA[bufi][c * 8]);
        }
    };
    auto loadA_f32 = [&](int k0) {
        const float4* g = (const float4*)(Af + (size_t)(m0 + ar) * K + k0 + ah);
        fa0 = g[0]; fa1 = g[1]; fa2 = g[2]; fa3 = g[3];
    };
    auto writeA_f32 = [&](int bufi) {
        ushort* d = &sA[bufi][ar * 32 + ah];
        bf16x8 lo, hi;
        lo[0] = (short)f2bf(fa0.x); lo[1] = (short)f2bf(fa0.y);
        lo[2] = (short)f2bf(fa0.z); lo[3] = (short)f2bf(fa0.w);
        lo[4] = (short)f2bf(fa1.x); lo[5] = (short)f2bf(fa1.y);
        lo[6] = (short)f2bf(fa1.z); lo[7] = (short)f2bf(fa1.w);
        hi[0] = (short)f2bf(fa2.x); hi[1] = (short)f2bf(fa2.y);
        hi[2] = (short)f2bf(fa2.z); hi[3] = (short)f2bf(fa2.w);
        hi[4] = (short)f2bf(fa3.x); hi[5] = (short)f2bf(fa3.y);
        hi[6] = (short)f2bf(fa3.z); hi[7] = (short)f2bf(fa3.w);
        *(bf16x8*)&d[0] = lo;
        *(bf16x8*)&d[8] = hi;
    };
    auto compute = [&](int bufi) {
        bf16x8 af[4], bfr[4];
        #pragma unroll
        for (int m = 0; m < 4; m++)
            af[m] = *(const bf16x8*)&sA[bufi][(wr * 64 + m * 16 + lr) * 32 + kb * 8];
        #pragma unroll
        for (int n = 0; n < 4; n++)
            bfr[n] = *(const bf16x8*)&sB[bufi][(wc * 64 + n * 16 + lr) * 32 + kb * 8];
        #pragma unroll
        for (int m = 0; m < 4; m++)
            #pragma unroll
            for (int n = 0; n < 4; n++)
                acc[m][n] = __builtin_amdgcn_mfma_f32_16x16x32_bf16(af[m], bfr[n], acc[m][n], 0, 0, 0);
    };

    // prologue: stage tile 0 into buffer 0
    if (A_F32) { loadA_f32(0); writeA_f32(0); }
    else       { stageA_bf(0, 0); }
    stageB(0, 0);
    __syncthreads();

    const int nt = K / 32;
    int cur = 0;
    for (int t = 0; t < nt - 1; t++) {
        const int k0n = (t + 1) * 32;
        // issue next-tile loads before computing current
        if (A_F32) { loadA_f32(k0n); }
        else       { stageA_bf(k0n, cur ^ 1); }
        stageB(k0n, cur ^ 1);
        compute(cur);
        if (A_F32) writeA_f32(cur ^ 1);   // cvt+ds_write after MFMA (latency hidden)
        __syncthreads();
        cur ^= 1;
    }
    compute(cur);

    float*  Cf = (float*)Cv;
    ushort* Cb = (ushort*)Cv;
    #pragma unroll
    for (int m = 0; m < 4; m++) {
        #pragma unroll
        for (int n = 0; n < 4; n++) {
            #pragma unroll
            for (int r = 0; r < 4; r++) {
                int row = m0 + wr * 64 + m * 16 + (lane >> 4) * 4 + r;
                int col = n0 + wc * 64 + n * 16 + (lane & 15);
                float v = acc[m][n][r];
                if (EPI == 1) v = 1.0f / (1.0f + __expf(-v));
                else if (EPI == 2) v = __expf(v);
                size_t idx = (size_t)row * N + col;
                if (OUT_BF) Cb[idx] = f2bf(v);
                else        Cf[idx] = v;
            }
        }
    }
}

// ---------------- scan pass A: per-chunk sums (bf16 in, ushort4 loads) ----------------
// partials layout: [chunk][b*H + h]
__global__ __launch_bounds__(256)
void scan_partials(const ushort* __restrict__ ke, const ushort* __restrict__ ev,
                   float* __restrict__ pke, float* __restrict__ pkv) {
    const int H = 1024, S = 8192, CHUNK = 32, BH = 4096;
    int h0 = threadIdx.x * 4;
    int c = blockIdx.x;
    int b = blockIdx.y;
    size_t base = ((size_t)b * S + (size_t)c * CHUNK) * H + h0;
    float se0 = 0.f, se1 = 0.f, se2 = 0.f, se3 = 0.f;
    float sv0 = 0.f, sv1 = 0.f, sv2 = 0.f, sv3 = 0.f;
    for (int s = 0; s < CHUNK; s++) {
        ushort4 e4 = *(const ushort4*)(ke + base + (size_t)s * H);
        ushort4 v4 = *(const ushort4*)(ev + base + (size_t)s * H);
        float e0 = bf2f(e4.x), e1 = bf2f(e4.y), e2 = bf2f(e4.z), e3 = bf2f(e4.w);
        se0 += e0; se1 += e1; se2 += e2; se3 += e3;
        sv0 += e0 * bf2f(v4.x); sv1 += e1 * bf2f(v4.y);
        sv2 += e2 * bf2f(v4.z); sv3 += e3 * bf2f(v4.w);
    }
    size_t p = (size_t)c * BH + b * H + h0;
    *(float4*)(pke + p) = make_float4(se0, se1, se2, se3);
    *(float4*)(pkv + p) = make_float4(sv0, sv1, sv2, sv3);
}

// ---------------- scan pass B: exclusive prefix over chunks ----------------
__global__ __launch_bounds__(256)
void scan_offsets(float* __restrict__ pke, float* __restrict__ pkv, int nch, int BH) {
    int i = blockIdx.x * blockDim.x + threadIdx.x;
    if (i >= BH) return;
    float rke = 0.f, rkv = 0.f;
    for (int c = 0; c < nch; c++) {
        size_t idx = (size_t)c * BH + i;
        float a = pke[idx], b = pkv[idx];
        pke[idx] = rke; pkv[idx] = rkv;
        rke += a; rkv += b;
    }
}

// ---------------- scan pass C: inclusive scan + y = sigmoid(emb_q)*(kv/ke), bf16 out ----------------
__global__ __launch_bounds__(256)
void scan_final(const ushort* __restrict__ ke, const ushort* __restrict__ ev,
                const ushort* __restrict__ sq,
                const float* __restrict__ pke, const float* __restrict__ pkv,
                ushort* __restrict__ ybf) {
    const int H = 1024, S = 8192, CHUNK = 32, BH = 4096;
    int h0 = threadIdx.x * 4;
    int c = blockIdx.x;
    int b = blockIdx.y;
    size_t p = (size_t)c * BH + b * H + h0;
    float4 rke = *(const float4*)(pke + p);
    float4 rkv = *(const float4*)(pkv + p);
    size_t base = ((size_t)b * S + (size_t)c * CHUNK) * H + h0;
    for (int s = 0; s < CHUNK; s++) {
        size_t idx = base + (size_t)s * H;
        ushort4 e4 = *(const ushort4*)(ke + idx);
        ushort4 v4 = *(const ushort4*)(ev + idx);
        ushort4 q4 = *(const ushort4*)(sq + idx);
        float e0 = bf2f(e4.x), e1 = bf2f(e4.y), e2 = bf2f(e4.z), e3 = bf2f(e4.w);
        rke.x += e0; rke.y += e1; rke.z += e2; rke.w += e3;
        rkv.x += e0 * bf2f(v4.x); rkv.y += e1 * bf2f(v4.y);
        rkv.z += e2 * bf2f(v4.z); rkv.w += e3 * bf2f(v4.w);
        ushort4 o;
        o.x = f2bf(bf2f(q4.x) * (rkv.x / rke.x));
        o.y = f2bf(bf2f(q4.y) * (rkv.y / rke.y));
        o.z = f2bf(bf2f(q4.z) * (rkv.z / rke.z));
        o.w = f2bf(bf2f(q4.w) * (rkv.w / rke.w));
        *(ushort4*)(ybf + idx) = o;
    }
}

extern "C" void kernel_launch(void* const* d_in, const int* in_sizes, int n_in,
                              void* d_out, int out_size, void* d_ws, size_t ws_size,
                              hipStream_t stream) {
    const float* q   = (const float*)d_in[0];
    const float* k   = (const float*)d_in[1];
    const float* v   = (const float*)d_in[2];
    const float* w_q = (const float*)d_in[3];
    const float* w_k = (const float*)d_in[4];
    const float* w_v = (const float*)d_in[5];
    const float* w_p = (const float*)d_in[6];
    float* out = (float*)d_out;

    const int B = 4, S = 8192, H = 1024;
    const int M = B * S;                  // 32768
    const size_t MH = (size_t)M * H;      // 33,554,432
    const int NCH = 256;                  // CHUNK = 32
    const int BH = B * H;                 // 4096

    char* ws = (char*)d_ws;
    size_t off = 0;
    auto alloc = [&](size_t bytes) -> char* {
        char* p = ws + off;
        off += (bytes + 255) & ~(size_t)255;
        return p;
    };
    ushort* ybuf = (ushort*)alloc(MH * 2);
    ushort* wqt  = (ushort*)alloc((size_t)H * H * 2);
    ushort* wkt  = (ushort*)alloc((size_t)H * H * 2);
    ushort* wvt  = (ushort*)alloc((size_t)H * H * 2);
    ushort* wpt  = (ushort*)alloc((size_t)H * H * 2);
    ushort* sqb  = (ushort*)alloc(MH * 2);
    ushort* keb  = (ushort*)alloc(MH * 2);
    ushort* evb  = (ushort*)alloc(MH * 2);
    float*  pke  = (float*)alloc((size_t)NCH * BH * 4);
    float*  pkv  = (float*)alloc((size_t)NCH * BH * 4);
    // total ~ 286 MB

    dim3 tg(H / 32, H / 32);
    dim3 gg((M / 128) * (H / 128));       // 1-D, swizzled in-kernel
    dim3 gs(NCH, B);

    transpose_to_bf16<<<tg, 256, 0, stream>>>(w_q, wqt, H, H);
    transpose_to_bf16<<<tg, 256, 0, stream>>>(w_k, wkt, H, H);
    transpose_to_bf16<<<tg, 256, 0, stream>>>(w_v, wvt, H, H);
    transpose_to_bf16<<<tg, 256, 0, stream>>>(w_p, wpt, H, H);

    // projections with fused cvt + epilogue, bf16 outputs
    gemm_bt<1, 1, 1><<<gg, 256, 0, stream>>>(q, wqt, sqb, M, H, H);
    gemm_bt<2, 1, 1><<<gg, 256, 0, stream>>>(k, wkt, keb, M, H, H);
    gemm_bt<0, 1, 1><<<gg, 256, 0, stream>>>(v, wvt, evb, M, H, H);

    // hierarchical scan over S
    scan_partials<<<gs, 256, 0, stream>>>(keb, evb, pke, pkv);
    scan_offsets<<<BH / 256, 256, 0, stream>>>(pke, pkv, NCH, BH);
    scan_final<<<gs, 256, 0, stream>>>(keb, evb, sqb, pke, pkv, ybuf);

    // out = y @ w_p (fp32 out)
    gemm_bt<0, 0, 0><<<gg, 256, 0, stream>>>(ybuf, wpt, out, M, H, H);
}

// Round 3
// 550.125 us; speedup vs baseline: 1.3939x; 1.2438x over previous
//
#include <hip/hip_runtime.h>
#include <hip/hip_bf16.h>
#include <cstdint>

#define AS_GLOBAL __attribute__((address_space(1)))
#define AS_LDS    __attribute__((address_space(3)))

typedef __attribute__((ext_vector_type(8))) short bf16x8;
typedef __attribute__((ext_vector_type(4))) float f32x4;

static __device__ __forceinline__ ushort f2bf(float x) {
    union { float f; uint32_t u; } c;
    c.f = x;
    uint32_t u = c.u;
    u += 0x7fffu + ((u >> 16) & 1u);   // RTNE
    return (ushort)(u >> 16);
}
static __device__ __forceinline__ float bf2f(ushort u) {
    union { uint32_t i; float f; } c;
    c.i = ((uint32_t)u) << 16;
    return c.f;
}

// async global->LDS, 16B/lane. LDS dest = wave-uniform base + lane*16 (we pass base+lane*16).
static __device__ __forceinline__ void gload_lds16(const void* g, void* l) {
    __builtin_amdgcn_global_load_lds(
        (const AS_GLOBAL uint32_t*)(uintptr_t)g,
        (AS_LDS uint32_t*)(uint32_t)(uintptr_t)l,
        16, 0, 0);
}

// ---------------- [K,N] fp32 -> [N,K] bf16 transpose ----------------
__global__ __launch_bounds__(256)
void transpose_to_bf16(const float* __restrict__ w, ushort* __restrict__ wt, int K, int N) {
    __shared__ float tile[32][33];
    int bn = blockIdx.x * 32;
    int bk = blockIdx.y * 32;
    int tx = threadIdx.x & 31, ty = threadIdx.x >> 5;
    #pragma unroll
    for (int i = 0; i < 32; i += 8)
        tile[ty + i][tx] = w[(size_t)(bk + ty + i) * N + bn + tx];
    __syncthreads();
    #pragma unroll
    for (int i = 0; i < 32; i += 8)
        wt[(size_t)(bn + ty + i) * K + bk + tx] = f2bf(tile[tx][ty + i]);
}

// =====================================================================
// 256x256 8-phase GEMM: C[M,1024] = A[M,1024] * Bt[1024,1024](bf16)
// M=32768 fixed. BK=64, nt=16 K-tiles, 8 iterations x 8 phases.
// EPI: 0=none 1=sigmoid 2=exp.  A_F32: fused fp32->bf16 A staging.  OUT_BF: bf16 C.
// =====================================================================
template<int EPI, int A_F32, int OUT_BF>
__global__ __launch_bounds__(512, 2)
void gemm256(const void* __restrict__ Av, const ushort* __restrict__ Bt,
             void* __restrict__ Cv) {
    constexpr int K = 1024, N = 1024;
    __shared__ ushort sA[2][16384];   // [buf][row*64 + physslot*8], 32KB each
    __shared__ ushort sB[2][16384];
    const int tid  = threadIdx.x;
    const int wid  = tid >> 6;
    const int lane = tid & 63;
    const int wr = wid >> 2, wc = wid & 3;        // 2 x 4 waves, each owns 128x64 of C
    const int lr = lane & 15, kb = lane >> 4;

    // XCD swizzle: 512 wgs = 8 xcds x 64; same-xcd blocks share a bm range (A reuse in L2)
    const int wg = blockIdx.x;
    const int xcd = wg & 7, local = wg >> 3;
    const int bm = xcd * 16 + (local >> 2);
    const int bn = local & 3;
    const int m0 = bm * 256, n0 = bn * 256;

    const float*  Af = (const float*)Av;
    const ushort* Ab = (const ushort*)Av;

    f32x4 acc[8][4] = {};
    float4 fa0, fa1, fa2, fa3;                    // in-flight fp32 A (reg stage)
    const int arl  = tid >> 2;                    // 0..127
    const int aseg = tid & 3;
    const int agr0 = ((arl >> 6) << 7) + (arl & 63);   // +h*64 -> row within tile

    // ---- staging helpers (LDS linear dest, pre-swizzled global source) ----
    auto stageB = [&](int tile, int h) {
        ushort* buf = sB[tile & 1];
        const int kt0 = tile * 64;
        #pragma unroll
        for (int j = 0; j < 2; j++) {
            const int row0 = j * 128 + h * 32 + (wid >> 2) * 64 + (wid & 3) * 8;
            const int row  = row0 + (lane >> 3);
            const int kslot = (lane & 7) ^ (lane >> 3);      // row&7 == lane>>3
            gload_lds16(Bt + (size_t)(n0 + row) * K + kt0 + kslot * 8,
                        &buf[row * 64 + (lane & 7) * 8]);
        }
    };
    auto stageAbf = [&](int tile, int h) {
        ushort* buf = sA[tile & 1];
        const int kt0 = tile * 64;
        #pragma unroll
        for (int j = 0; j < 2; j++) {
            const int row0 = j * 128 + h * 64 + wid * 8;
            const int row  = row0 + (lane >> 3);
            const int kslot = (lane & 7) ^ (lane >> 3);
            gload_lds16(Ab + (size_t)(m0 + row) * K + kt0 + kslot * 8,
                        &buf[row * 64 + (lane & 7) * 8]);
        }
    };
    auto issueA = [&](int tile, int h) {
        const int row = agr0 + h * 64;
        const float* s = Af + (size_t)(m0 + row) * K + tile * 64 + aseg * 16;
        fa0 = *(const float4*)(s);     fa1 = *(const float4*)(s + 4);
        fa2 = *(const float4*)(s + 8); fa3 = *(const float4*)(s + 12);
    };
    auto writeAcore = [&](int tile, int h) {
        const int row = agr0 + h * 64;
        const int ks0 = (aseg * 2) ^ (row & 7);
        ushort* buf = sA[tile & 1];
        bf16x8 lo, hi;
        lo[0]=(short)f2bf(fa0.x); lo[1]=(short)f2bf(fa0.y); lo[2]=(short)f2bf(fa0.z); lo[3]=(short)f2bf(fa0.w);
        lo[4]=(short)f2bf(fa1.x); lo[5]=(short)f2bf(fa1.y); lo[6]=(short)f2bf(fa1.z); lo[7]=(short)f2bf(fa1.w);
        hi[0]=(short)f2bf(fa2.x); hi[1]=(short)f2bf(fa2.y); hi[2]=(short)f2bf(fa2.z); hi[3]=(short)f2bf(fa2.w);
        hi[4]=(short)f2bf(fa3.x); hi[5]=(short)f2bf(fa3.y); hi[6]=(short)f2bf(fa3.z); hi[7]=(short)f2bf(fa3.w);
        *(bf16x8*)&buf[row * 64 + ks0 * 8]       = lo;
        *(bf16x8*)&buf[row * 64 + (ks0 ^ 1) * 8] = hi;
    };
    auto writeA = [&](int tile, int h) {
        asm volatile("s_waitcnt vmcnt(2)" ::: "memory");   // fa loads done; prev B stays in flight
        writeAcore(tile, h);
        asm volatile("s_waitcnt lgkmcnt(0)" ::: "memory"); // LDS write visible before barrier
    };

    // ---- prologue: fully stage tiles 0 and 1 ----
    if (A_F32) {
        #pragma unroll
        for (int x = 0; x < 2; x++)
            #pragma unroll
            for (int h = 0; h < 2; h++) {
                issueA(x, h);
                asm volatile("s_waitcnt vmcnt(0)" ::: "memory");
                writeAcore(x, h);
            }
    } else {
        #pragma unroll
        for (int x = 0; x < 2; x++) { stageAbf(x, 0); stageAbf(x, 1); }
    }
    #pragma unroll
    for (int x = 0; x < 2; x++) { stageB(x, 0); stageB(x, 1); }
    asm volatile("s_waitcnt vmcnt(0)" ::: "memory");
    __syncthreads();

// one phase: 12 ds_read frags | stage | vmcnt(6) | barrier | 16 MFMA | barrier
#define PHASE(TOFF, MQ, NQ, STAGE_BLOCK) { \
    const ushort* pA = sA[(t0 + TOFF) & 1]; \
    const ushort* pB = sB[(t0 + TOFF) & 1]; \
    bf16x8 af[4][2], bv[2][2]; \
    _Pragma("unroll") for (int m = 0; m < 4; m++) \
      _Pragma("unroll") for (int kh = 0; kh < 2; kh++) \
        af[m][kh] = *(const bf16x8*)&pA[(wr*128 + MQ*64 + m*16 + lr)*64 + (((kh*4+kb) ^ (lr&7)))*8]; \
    _Pragma("unroll") for (int n = 0; n < 2; n++) \
      _Pragma("unroll") for (int kh = 0; kh < 2; kh++) \
        bv[n][kh] = *(const bf16x8*)&pB[(wc*64 + NQ*32 + n*16 + lr)*64 + (((kh*4+kb) ^ (lr&7)))*8]; \
    STAGE_BLOCK \
    asm volatile("s_waitcnt vmcnt(6)" ::: "memory"); \
    asm volatile("" ::: "memory"); \
    __builtin_amdgcn_s_barrier(); \
    asm volatile("" ::: "memory"); \
    __builtin_amdgcn_s_setprio(1); \
    _Pragma("unroll") for (int m = 0; m < 4; m++) \
      _Pragma("unroll") for (int n = 0; n < 2; n++) { \
        acc[MQ*4+m][NQ*2+n] = __builtin_amdgcn_mfma_f32_16x16x32_bf16(af[m][0], bv[n][0], acc[MQ*4+m][NQ*2+n], 0, 0, 0); \
        acc[MQ*4+m][NQ*2+n] = __builtin_amdgcn_mfma_f32_16x16x32_bf16(af[m][1], bv[n][1], acc[MQ*4+m][NQ*2+n], 0, 0, 0); \
      } \
    __builtin_amdgcn_s_setprio(0); \
    asm volatile("" ::: "memory"); \
    __builtin_amdgcn_s_barrier(); \
    asm volatile("" ::: "memory"); \
}

    // ---- main loop: 8 iterations, 2 K-tiles each ----
    for (int i = 0; i < 8; i++) {
        const int t0 = 2 * i;
        // p0: tile t0, quad (0,0)
        PHASE(0, 0, 0, {
            if (i > 0) {
                if (A_F32) writeA(t0 + 1, 0); 
                if (A_F32) issueA(t0 + 1, 1); else stageAbf(t0 + 1, 1);
            }
        })
        // p1: (0,1)
        PHASE(0, 0, 1, { if (i > 0) stageB(t0 + 1, 1); })
        // p2: (1,0)
        PHASE(0, 1, 0, {
            if (A_F32 && i > 0) writeA(t0 + 1, 1);
            if (i < 7) { if (A_F32) issueA(t0 + 2, 0); else stageAbf(t0 + 2, 0); }
        })
        // p3: (1,1)  [tail drain at last iteration]
        PHASE(0, 1, 1, {
            if (i < 7) stageB(t0 + 2, 0);
            if (i == 7) asm volatile("s_waitcnt vmcnt(0)" ::: "memory");
        })
        // p4: tile t0+1, quad (0,0)
        PHASE(1, 0, 0, {
            if (i < 7) {
                if (A_F32) writeA(t0 + 2, 0);
                if (A_F32) issueA(t0 + 2, 1); else stageAbf(t0 + 2, 1);
            }
        })
        // p5: (0,1)
        PHASE(1, 0, 1, { if (i < 7) stageB(t0 + 2, 1); })
        // p6: (1,0)
        PHASE(1, 1, 0, {
            if (i < 7) {
                if (A_F32) writeA(t0 + 2, 1);
                if (A_F32) issueA(t0 + 3, 0); else stageAbf(t0 + 3, 0);
            }
        })
        // p7: (1,1)
        PHASE(1, 1, 1, { if (i < 7) stageB(t0 + 3, 0); })
    }
#undef PHASE

    // ---- epilogue ----
    float*  Cf = (float*)Cv;
    ushort* Cb = (ushort*)Cv;
    #pragma unroll
    for (int fm = 0; fm < 8; fm++) {
        #pragma unroll
        for (int fn = 0; fn < 4; fn++) {
            #pragma unroll
            for (int r = 0; r < 4; r++) {
                int row = m0 + wr * 128 + fm * 16 + (lane >> 4) * 4 + r;
                int col = n0 + wc * 64 + fn * 16 + lr;
                float v = acc[fm][fn][r];
                if (EPI == 1) v = 1.0f / (1.0f + __expf(-v));
                else if (EPI == 2) v = __expf(v);
                size_t idx = (size_t)row * N + col;
                if (OUT_BF) Cb[idx] = f2bf(v);
                else        Cf[idx] = v;
            }
        }
    }
}

// ---------------- scan pass A: per-chunk sums (bf16 in) ----------------
__global__ __launch_bounds__(256)
void scan_partials(const ushort* __restrict__ ke, const ushort* __restrict__ ev,
                   float* __restrict__ pke, float* __restrict__ pkv) {
    const int H = 1024, S = 8192, CHUNK = 32, BH = 4096;
    int h0 = threadIdx.x * 4;
    int c = blockIdx.x;
    int b = blockIdx.y;
    size_t base = ((size_t)b * S + (size_t)c * CHUNK) * H + h0;
    float se0 = 0.f, se1 = 0.f, se2 = 0.f, se3 = 0.f;
    float sv0 = 0.f, sv1 = 0.f, sv2 = 0.f, sv3 = 0.f;
    for (int s = 0; s < CHUNK; s++) {
        ushort4 e4 = *(const ushort4*)(ke + base + (size_t)s * H);
        ushort4 v4 = *(const ushort4*)(ev + base + (size_t)s * H);
        float e0 = bf2f(e4.x), e1 = bf2f(e4.y), e2 = bf2f(e4.z), e3 = bf2f(e4.w);
        se0 += e0; se1 += e1; se2 += e2; se3 += e3;
        sv0 += e0 * bf2f(v4.x); sv1 += e1 * bf2f(v4.y);
        sv2 += e2 * bf2f(v4.z); sv3 += e3 * bf2f(v4.w);
    }
    size_t p = (size_t)c * BH + b * H + h0;
    *(float4*)(pke + p) = make_float4(se0, se1, se2, se3);
    *(float4*)(pkv + p) = make_float4(sv0, sv1, sv2, sv3);
}

// ---------------- scan pass B: exclusive prefix over chunks ----------------
__global__ __launch_bounds__(256)
void scan_offsets(float* __restrict__ pke, float* __restrict__ pkv, int nch, int BH) {
    int i = blockIdx.x * blockDim.x + threadIdx.x;
    if (i >= BH) return;
    float rke = 0.f, rkv = 0.f;
    for (int c = 0; c < nch; c++) {
        size_t idx = (size_t)c * BH + i;
        float a = pke[idx], b = pkv[idx];
        pke[idx] = rke; pkv[idx] = rkv;
        rke += a; rkv += b;
    }
}

// ---------------- scan pass C: inclusive scan + y = sigmoid(emb_q)*(kv/ke) ----------------
__global__ __launch_bounds__(256)
void scan_final(const ushort* __restrict__ ke, const ushort* __restrict__ ev,
                const ushort* __restrict__ sq,
                const float* __restrict__ pke, const float* __restrict__ pkv,
                ushort* __restrict__ ybf) {
    const int H = 1024, S = 8192, CHUNK = 32, BH = 4096;
    int h0 = threadIdx.x * 4;
    int c = blockIdx.x;
    int b = blockIdx.y;
    size_t p = (size_t)c * BH + b * H + h0;
    float4 rke = *(const float4*)(pke + p);
    float4 rkv = *(const float4*)(pkv + p);
    size_t base = ((size_t)b * S + (size_t)c * CHUNK) * H + h0;
    for (int s = 0; s < CHUNK; s++) {
        size_t idx = base + (size_t)s * H;
        ushort4 e4 = *(const ushort4*)(ke + idx);
        ushort4 v4 = *(const ushort4*)(ev + idx);
        ushort4 q4 = *(const ushort4*)(sq + idx);
        float e0 = bf2f(e4.x), e1 = bf2f(e4.y), e2 = bf2f(e4.z), e3 = bf2f(e4.w);
        rke.x += e0; rke.y += e1; rke.z += e2; rke.w += e3;
        rkv.x += e0 * bf2f(v4.x); rkv.y += e1 * bf2f(v4.y);
        rkv.z += e2 * bf2f(v4.z); rkv.w += e3 * bf2f(v4.w);
        ushort4 o;
        o.x = f2bf(bf2f(q4.x) * (rkv.x / rke.x));
        o.y = f2bf(bf2f(q4.y) * (rkv.y / rke.y));
        o.z = f2bf(bf2f(q4.z) * (rkv.z / rke.z));
        o.w = f2bf(bf2f(q4.w) * (rkv.w / rke.w));
        *(ushort4*)(ybf + idx) = o;
    }
}

extern "C" void kernel_launch(void* const* d_in, const int* in_sizes, int n_in,
                              void* d_out, int out_size, void* d_ws, size_t ws_size,
                              hipStream_t stream) {
    const float* q   = (const float*)d_in[0];
    const float* k   = (const float*)d_in[1];
    const float* v   = (const float*)d_in[2];
    const float* w_q = (const float*)d_in[3];
    const float* w_k = (const float*)d_in[4];
    const float* w_v = (const float*)d_in[5];
    const float* w_p = (const float*)d_in[6];
    float* out = (float*)d_out;

    const int B = 4, S = 8192, H = 1024;
    const int M = B * S;                  // 32768
    const size_t MH = (size_t)M * H;      // 33,554,432
    const int NCH = 256;                  // CHUNK = 32
    const int BH = B * H;                 // 4096

    char* ws = (char*)d_ws;
    size_t off = 0;
    auto alloc = [&](size_t bytes) -> char* {
        char* p = ws + off;
        off += (bytes + 255) & ~(size_t)255;
        return p;
    };
    ushort* ybuf = (ushort*)alloc(MH * 2);
    ushort* wqt  = (ushort*)alloc((size_t)H * H * 2);
    ushort* wkt  = (ushort*)alloc((size_t)H * H * 2);
    ushort* wvt  = (ushort*)alloc((size_t)H * H * 2);
    ushort* wpt  = (ushort*)alloc((size_t)H * H * 2);
    ushort* sqb  = (ushort*)alloc(MH * 2);
    ushort* keb  = (ushort*)alloc(MH * 2);
    ushort* evb  = (ushort*)alloc(MH * 2);
    float*  pke  = (float*)alloc((size_t)NCH * BH * 4);
    float*  pkv  = (float*)alloc((size_t)NCH * BH * 4);

    dim3 tg(H / 32, H / 32);
    const int ngg = (M / 256) * (H / 256);   // 512 blocks
    dim3 gs(NCH, B);

    transpose_to_bf16<<<tg, 256, 0, stream>>>(w_q, wqt, H, H);
    transpose_to_bf16<<<tg, 256, 0, stream>>>(w_k, wkt, H, H);
    transpose_to_bf16<<<tg, 256, 0, stream>>>(w_v, wvt, H, H);
    transpose_to_bf16<<<tg, 256, 0, stream>>>(w_p, wpt, H, H);

    // projections: fused fp32->bf16 A staging + epilogue, bf16 outputs
    gemm256<1, 1, 1><<<ngg, 512, 0, stream>>>(q, wqt, sqb);
    gemm256<2, 1, 1><<<ngg, 512, 0, stream>>>(k, wkt, keb);
    gemm256<0, 1, 1><<<ngg, 512, 0, stream>>>(v, wvt, evb);

    // hierarchical scan over S
    scan_partials<<<gs, 256, 0, stream>>>(keb, evb, pke, pkv);
    scan_offsets<<<BH / 256, 256, 0, stream>>>(pke, pkv, NCH, BH);
    scan_final<<<gs, 256, 0, stream>>>(keb, evb, sqb, pke, pkv, ybuf);

    // out = y @ w_p (bf16 A via global_load_lds, fp32 out)
    gemm256<0, 0, 0><<<ngg, 512, 0, stream>>>(ybuf, wpt, out);
}